// Round 1
// baseline (33.149 us; speedup 1.0000x reference)
//
#include <hip/hip_runtime.h>

typedef _Float16 h2 __attribute__((ext_vector_type(2)));
typedef _Float16 h8 __attribute__((ext_vector_type(8)));

#define RANK  16
#define GRIDP 128
#define BLOCK 256
#define NBLK  1024

union H8 { h8 v; h2 p[4]; };

__device__ __forceinline__ float fdot2(h2 a, h2 b, float c) {
#if __has_builtin(__builtin_amdgcn_fdot2)
    return __builtin_amdgcn_fdot2(a, b, c, false);
#else
    return (float)a.x * (float)b.x + (float)a.y * (float)b.y + c;
#endif
}

__global__ __launch_bounds__(BLOCK) void pinn_lora_kernel(
    const float* __restrict__ x, const float* __restrict__ line,
    const float* __restrict__ W, float* __restrict__ out, int ngroups)
{
    // fp16 table, transposed to [axis][g][rank] so one grid row = 32 B contiguous
    __shared__ h8 tab[3][GRIDP][2];

    // stage: coalesced f32 read of line_vec [a][r][g] -> fp16 LDS [a][g][r]
    _Float16* t = (_Float16*)tab;
    for (int i = threadIdx.x; i < 3 * RANK * GRIDP; i += BLOCK) {
        int a   = i >> 11;        // / (16*128)
        int rem = i & 2047;
        int r   = rem >> 7;       // / 128
        int g   = rem & 127;
        t[(a << 11) + (g << 4) + r] = (_Float16)line[i];
    }

    // W[3][16] f32 -> packed f16 in registers (uniform addresses -> scalar loads)
    h2 Wp[3][8];
#pragma unroll
    for (int o = 0; o < 3; ++o)
#pragma unroll
        for (int d = 0; d < 8; ++d) {
            Wp[o][d].x = (_Float16)W[o * 16 + 2 * d];
            Wp[o][d].y = (_Float16)W[o * 16 + 2 * d + 1];
        }

    __syncthreads();

    const float4* xv = (const float4*)x;
    float4*       ov = (float4*)out;

    int tid    = blockIdx.x * BLOCK + threadIdx.x;
    int stride = gridDim.x * BLOCK;

    for (int g = tid; g < ngroups; g += stride) {
        float4 c0 = xv[3 * g + 0];
        float4 c1 = xv[3 * g + 1];
        float4 c2 = xv[3 * g + 2];

        // 4 points per group; x layout [N][3]
        float cx[4] = {c0.x, c0.w, c1.z, c2.y};   // x[:,0]
        float cy[4] = {c0.y, c1.x, c1.w, c2.z};   // x[:,1]
        float cz[4] = {c0.z, c1.y, c2.x, c2.w};   // x[:,2]

        float o[4][3];
#pragma unroll
        for (int p = 0; p < 4; ++p) {
            // axis a interpolates coord x[:, 2-a]
            float crd[3] = {cz[p], cy[p], cx[p]};
            H8 prod0, prod1;
#pragma unroll
            for (int a = 0; a < 3; ++a) {
                float pos = fmaf(crd[a], 63.5f, 63.5f);
                int   i0  = (int)floorf(pos);
                i0 = (i0 < 0) ? 0 : ((i0 > 126) ? 126 : i0);
                float w = pos - (float)i0;
                _Float16 wh = (_Float16)w;
                h2 w2; w2.x = wh; w2.y = wh;

                const h8* row = &tab[a][i0][0];
                H8 A0, A1, B0, B1;
                A0.v = row[0]; A1.v = row[1];   // row i0   (16 f16)
                B0.v = row[2]; B1.v = row[3];   // row i0+1 (16 f16)

                H8 v0, v1;
#pragma unroll
                for (int j = 0; j < 4; ++j) {
                    v0.p[j] = A0.p[j] + (B0.p[j] - A0.p[j]) * w2;
                    v1.p[j] = A1.p[j] + (B1.p[j] - A1.p[j]) * w2;
                }
                if (a == 0) { prod0 = v0; prod1 = v1; }
                else {
#pragma unroll
                    for (int j = 0; j < 4; ++j) {
                        prod0.p[j] *= v0.p[j];
                        prod1.p[j] *= v1.p[j];
                    }
                }
            }
#pragma unroll
            for (int oo = 0; oo < 3; ++oo) {
                float acc = 0.f;
#pragma unroll
                for (int j = 0; j < 4; ++j) {
                    acc = fdot2(prod0.p[j], Wp[oo][j],     acc);
                    acc = fdot2(prod1.p[j], Wp[oo][j + 4], acc);
                }
                o[p][oo] = acc;
            }
        }

        float4 s0 = {o[0][0], o[0][1], o[0][2], o[1][0]};
        float4 s1 = {o[1][1], o[1][2], o[2][0], o[2][1]};
        float4 s2 = {o[2][2], o[3][0], o[3][1], o[3][2]};
        ov[3 * g + 0] = s0;
        ov[3 * g + 1] = s1;
        ov[3 * g + 2] = s2;
    }
}

extern "C" void kernel_launch(void* const* d_in, const int* in_sizes, int n_in,
                              void* d_out, int out_size, void* d_ws, size_t ws_size,
                              hipStream_t stream) {
    const float* x    = (const float*)d_in[0];   // [N,3] f32
    const float* line = (const float*)d_in[1];   // [3,16,128] f32
    const float* W    = (const float*)d_in[2];   // [3,16] f32
    float*       out  = (float*)d_out;           // [N,3] f32

    int npts    = in_sizes[0] / 3;
    int ngroups = npts / 4;                      // N = 2^22, divisible

    pinn_lora_kernel<<<NBLK, BLOCK, 0, stream>>>(x, line, W, out, ngroups);
}

// Round 2
// 31.241 us; speedup vs baseline: 1.0611x; 1.0611x over previous
//
#include <hip/hip_runtime.h>

typedef _Float16 h2 __attribute__((ext_vector_type(2)));
typedef _Float16 h8 __attribute__((ext_vector_type(8)));

#define RANK  16
#define GRIDP 128
#define BLOCK 256
#define NBLK  2048

union H8 { h8 v; h2 p[4]; };

__device__ __forceinline__ float fdot2(h2 a, h2 b, float c) {
#if __has_builtin(__builtin_amdgcn_fdot2)
    return __builtin_amdgcn_fdot2(a, b, c, false);
#else
    return (float)a.x * (float)b.x + (float)a.y * (float)b.y + c;
#endif
}

__global__ __launch_bounds__(BLOCK) void pinn_lora_kernel(
    const float* __restrict__ x, const float* __restrict__ line,
    const float* __restrict__ W, float* __restrict__ out, int ngroups)
{
    // Chunked fp16 table: tab[a][c][g] holds ranks 8c..8c+7 of grid row g.
    // Byte address of tab[a][c][g] = ((a*2+c)*128 + g) * 16
    //   -> bank-quad = g & 7  (8 classes for random g, vs 4 with [a][g][rank])
    __shared__ h8 tab[3][2][GRIDP];

    _Float16* t = (_Float16*)tab;
    for (int i = threadIdx.x; i < 3 * RANK * GRIDP; i += BLOCK) {
        int a = i >> 11;          // / (16*128)
        int r = (i >> 7) & 15;    // rank
        int g = i & 127;          // grid row
        int c = r >> 3;           // rank half
        t[((((a << 1) + c) << 7) + g) * 8 + (r & 7)] = (_Float16)line[i];
    }

    // W[3][16] f32 -> packed f16 (uniform addresses -> scalar loads)
    h2 Wp[3][8];
#pragma unroll
    for (int o = 0; o < 3; ++o)
#pragma unroll
        for (int d = 0; d < 8; ++d) {
            Wp[o][d].x = (_Float16)W[o * 16 + 2 * d];
            Wp[o][d].y = (_Float16)W[o * 16 + 2 * d + 1];
        }

    __syncthreads();

    const float4* xv = (const float4*)x;
    float4*       ov = (float4*)out;

    int tid    = blockIdx.x * BLOCK + threadIdx.x;
    int stride = gridDim.x * BLOCK;

    for (int g = tid; g < ngroups; g += stride) {
        float4 c0 = xv[3 * g + 0];
        float4 c1 = xv[3 * g + 1];
        float4 c2 = xv[3 * g + 2];

        // 4 points per group; x layout [N][3]
        float cx[4] = {c0.x, c0.w, c1.z, c2.y};   // x[:,0]
        float cy[4] = {c0.y, c1.x, c1.w, c2.z};   // x[:,1]
        float cz[4] = {c0.z, c1.y, c2.x, c2.w};   // x[:,2]

        float o[4][3];
#pragma unroll
        for (int p = 0; p < 4; ++p) {
            // axis a interpolates coord x[:, 2-a]
            float crd[3] = {cz[p], cy[p], cx[p]};
            H8 prod0, prod1;
#pragma unroll
            for (int a = 0; a < 3; ++a) {
                float pos = fmaf(crd[a], 63.5f, 63.5f);
                int   i0  = (int)pos;              // pos >= 0 -> trunc == floor
                i0 = (i0 < 0) ? 0 : ((i0 > 126) ? 126 : i0);
                float w = pos - (float)i0;
                _Float16 wh = (_Float16)w;
                h2 w2; w2.x = wh; w2.y = wh;

                H8 A0, A1, B0, B1;
                A0.v = tab[a][0][i0];     // row i0,   ranks 0..7
                B0.v = tab[a][0][i0 + 1]; // row i0+1, ranks 0..7
                A1.v = tab[a][1][i0];     // row i0,   ranks 8..15
                B1.v = tab[a][1][i0 + 1]; // row i0+1, ranks 8..15

                H8 v0, v1;
#pragma unroll
                for (int j = 0; j < 4; ++j) {
                    v0.p[j] = A0.p[j] + (B0.p[j] - A0.p[j]) * w2;
                    v1.p[j] = A1.p[j] + (B1.p[j] - A1.p[j]) * w2;
                }
                if (a == 0) { prod0 = v0; prod1 = v1; }
                else {
#pragma unroll
                    for (int j = 0; j < 4; ++j) {
                        prod0.p[j] *= v0.p[j];
                        prod1.p[j] *= v1.p[j];
                    }
                }
            }
#pragma unroll
            for (int oo = 0; oo < 3; ++oo) {
                float acc = 0.f;
#pragma unroll
                for (int j = 0; j < 4; ++j) {
                    acc = fdot2(prod0.p[j], Wp[oo][j],     acc);
                    acc = fdot2(prod1.p[j], Wp[oo][j + 4], acc);
                }
                o[p][oo] = acc;
            }
        }

        float4 s0 = {o[0][0], o[0][1], o[0][2], o[1][0]};
        float4 s1 = {o[1][1], o[1][2], o[2][0], o[2][1]};
        float4 s2 = {o[2][2], o[3][0], o[3][1], o[3][2]};
        ov[3 * g + 0] = s0;
        ov[3 * g + 1] = s1;
        ov[3 * g + 2] = s2;
    }
}

extern "C" void kernel_launch(void* const* d_in, const int* in_sizes, int n_in,
                              void* d_out, int out_size, void* d_ws, size_t ws_size,
                              hipStream_t stream) {
    const float* x    = (const float*)d_in[0];   // [N,3] f32
    const float* line = (const float*)d_in[1];   // [3,16,128] f32
    const float* W    = (const float*)d_in[2];   // [3,16] f32
    float*       out  = (float*)d_out;           // [N,3] f32

    int npts    = in_sizes[0] / 3;
    int ngroups = npts / 4;                      // N = 2^22, divisible by 4

    pinn_lora_kernel<<<NBLK, BLOCK, 0, stream>>>(x, line, W, out, ngroups);
}